// Round 3
// baseline (226.292 us; speedup 1.0000x reference)
//
#include <hip/hip_runtime.h>
#include <math.h>

// EvidNets R17: R16 structure + amdgpu_waves_per_eu(4,4) pin on gemm_comb.
//   A_c(b) = prod_k (1 - s_kb*(1-U_kc)),  N(b) = prod_k (1 - s_kb)
//   out[b][c<20] = (A_c-N)/K, out[b][20] = N/K, K = sum_c A_c - 19N
//   s_kb = alphap_k * exp(-gamma_k^2*(0.5*(|W_k|^2+|x_b|^2) - W_k.x_b))
// R16 post-mortem: fusing the OUT tail flipped the backend occupancy
// heuristic to target 8 waves/EU -> VGPR_Count=64 < ~110 live -> L2-resident
// scratch spills (MfmaUtil 3%, VALUBusy 9%, HBM 2%, 164us). R4/R8's lesson
// was about the min-waves FLOOR being too high for 3-chain pressure; the
// current failure is the compiler's self-chosen CEILING too low. Fix: pin
// waves_per_eu to exactly (4,4) -> 128-VGPR budget == the LDS-limited
// occupancy (64.5KB -> 2 blocks/CU -> 4 waves/SIMD), which fits the 110-live
// body with headroom. Everything else identical to R16 (pair handoff fuses
// the old `finish` dispatch: second block of each sample pair merges PP
// partials and writes OUT).

#define NBATCH 16384
#define ND     256
#define NP     512
#define NCLS   20
#define OC     21

typedef short  short8  __attribute__((ext_vector_type(8)));
typedef short  short4v __attribute__((ext_vector_type(4)));
typedef unsigned short ushort8 __attribute__((ext_vector_type(8)));
typedef float  f32x16  __attribute__((ext_vector_type(16)));

// ---- workspace layout (bytes) ----
#define OFF_PWH 0u
#define OFF_PWL 262144u
#define OFF_VS  524288u                 // float VS[21][512] = 1-U (row 20 = 1)
#define OFF_WQ  567296u
#define OFF_AP  569344u
#define OFF_G2  571392u
#define OFF_FLG 573440u                 // int FLAGS[256], zeroed by prep each launch
#define OFF_PP  1048576u                // float PP[512][21*64] = 2.75 MB
#define WS_BIG  ((size_t)(OFF_PP + 2752512u))

__device__ __forceinline__ unsigned short f2bf_rn(float f) {
  unsigned int u = __float_as_uint(f);
  unsigned int r = (u + 0x7FFFu + ((u >> 16) & 1u)) >> 16;   // RNE (finite inputs)
  return (unsigned short)r;
}
__device__ __forceinline__ float bf2f(unsigned short h) {
  return __uint_as_float(((unsigned int)h) << 16);
}

// Combined prep: blocks 0..63 pack W[512][256] -> MFMA B-fragment order hi/lo
// bf16 + row sum-squares; blocks 64..65 build VS/AP/G2 tables; block 66 zeroes
// the pair-handoff flags (workspace is re-poisoned between iterations).
// frag elem (tile,step,lane,j) = src[tile*32+(lane&31)][step*16+8*(lane>>5)+j]
__global__ __launch_bounds__(256)
void prep(const float* __restrict__ Wsrc, const float* __restrict__ BETA,
          const float* __restrict__ alpha, const float* __restrict__ gamma,
          unsigned short* __restrict__ dh, unsigned short* __restrict__ dl,
          float* __restrict__ sq, float* __restrict__ VS,
          float* __restrict__ AP, float* __restrict__ G2,
          int* __restrict__ FLG)
{
  const int bid = blockIdx.x;
  if (bid < 64) {                      // ---- pack W ----
    const int tid = bid * 256 + threadIdx.x;
    const int row = tid >> 5, seg = tid & 31;
    const float4* s4 = (const float4*)(Wsrc + (size_t)row * ND + seg * 8);
    const float4 a = s4[0], b = s4[1];
    const float v[8] = {a.x, a.y, a.z, a.w, b.x, b.y, b.z, b.w};
    ushort8 hv, lv;
    float ssq = 0.f;
    #pragma unroll
    for (int j = 0; j < 8; ++j) {
      ssq = fmaf(v[j], v[j], ssq);
      const unsigned short hh = f2bf_rn(v[j]);
      hv[j] = hh;
      lv[j] = f2bf_rn(v[j] - bf2f(hh));
    }
    const int tile = row >> 5, m = row & 31, step = seg >> 1, r = seg & 1;
    const size_t cidx = (size_t)(tile * 16 + step) * 64 + m + 32 * r;
    *(ushort8*)(dh + cidx * 8) = hv;
    *(ushort8*)(dl + cidx * 8) = lv;
    #pragma unroll
    for (int off = 1; off < 32; off <<= 1) ssq += __shfl_xor(ssq, off, 64);
    if (seg == 0) sq[row] = ssq;
  } else if (bid < 66) {               // ---- scalar tables ----
    const int k = (bid - 64) * 256 + threadIdx.x;
    if (k >= NP) return;
    float bv[NCLS], bs = 0.f;
    #pragma unroll
    for (int c = 0; c < NCLS; ++c) { bv[c] = BETA[k * NCLS + c]; bs = fmaf(bv[c], bv[c], bs); }
    const float binv = 1.f / bs;
    #pragma unroll
    for (int c = 0; c < NCLS; ++c) VS[c * NP + k] = 1.f - bv[c] * bv[c] * binv;
    VS[NCLS * NP + k] = 1.f;
    AP[k] = 0.99f / (1.f + __expf(-alpha[k]));
    const float g = gamma[k];
    G2[k] = g * g;
  } else {                             // ---- zero handoff flags ----
    FLG[threadIdx.x] = 0;
  }
}

// One MFMA pass over sample-half sh: 32x32 tile, K=256, hi/lo split in TWO
// acc chains (accA = ah*bh; accB = ah*bl + al*bh), epilogue s -> sout[16].
__device__ __forceinline__ void mfma_pass(
    const short* __restrict__ Ah, const short* __restrict__ Al,
    const short8* __restrict__ bHc, const short8* __restrict__ bLc,
    const int lane, const int sh, const float* __restrict__ xqs,
    const float wqk, const float apk, const float g2k, float* __restrict__ sout)
{
  short8 wbh[4], wbl[4];
  #pragma unroll
  for (int p = 0; p < 4; ++p) { wbh[p] = bHc[p * 64]; wbl[p] = bLc[p * 64]; }

  f32x16 accA, accB;
  #pragma unroll
  for (int i = 0; i < 16; ++i) { accA[i] = 0.f; accB[i] = 0.f; }
  const short8* aH = (const short8*)Ah + (size_t)sh * 1024 + lane;
  const short8* aL = (const short8*)Al + (size_t)sh * 1024 + lane;
  #pragma unroll
  for (int step = 0; step < 16; ++step) {
    const short8 ah = aH[step * 64], al = aL[step * 64];
    const short8 bh = wbh[step & 3], bl = wbl[step & 3];
    if (step < 12) {
      wbh[step & 3] = bHc[(step + 4) * 64];
      wbl[step & 3] = bLc[(step + 4) * 64];
    }
    accA = __builtin_amdgcn_mfma_f32_32x32x16_bf16(ah, bh, accA, 0, 0, 0);
    accB = __builtin_amdgcn_mfma_f32_32x32x16_bf16(ah, bl, accB, 0, 0, 0);
    accB = __builtin_amdgcn_mfma_f32_32x32x16_bf16(al, bh, accB, 0, 0, 0);
  }
  // C/D: col(n)=lane&31 (proto), row(m)=(rg&3)+8*(rg>>2)+4*(lane>>5)
  const int h = lane >> 5;
  #pragma unroll
  for (int rg = 0; rg < 16; ++rg) {
    const int   m  = (rg & 3) + 8 * (rg >> 2) + 4 * h;
    const float dv = 0.5f * (wqk + xqs[sh * 32 + m]) - (accA[rg] + accB[rg]);
    sout[rg] = apk * __expf(-g2k * dv);
  }
}

// ---- main: 512 blocks x 512 thr. Block bx: samples (bx>>1)*64..+64,
// protos (bx&1)*256..+256. Wave wv owns 32 protos. LDS pool: A-frags
// (64KB) during MFMA, then swizzled s-tile sc[b][(p+4b)&255], then endgame.
// Writes partial PP[bx][c*64+b]; SECOND block of each pair (atomic ticket)
// merges both partials, normalizes, writes OUT.
// waves_per_eu(4,4): pin register budget to 128 (= LDS-limited occupancy);
// without it the backend targets 8 waves/EU -> 64 VGPRs -> scratch spills. ----
__global__ __launch_bounds__(512) __attribute__((amdgpu_waves_per_eu(4, 4)))
void gemm_comb(const float* __restrict__ X,
               const unsigned short* __restrict__ PWH, const unsigned short* __restrict__ PWL,
               const float* __restrict__ VS, const float* __restrict__ WQ,
               const float* __restrict__ AP, const float* __restrict__ G2,
               float* __restrict__ PP, int* __restrict__ FLG,
               float* __restrict__ OUT)
{
  __shared__ __align__(16) char pool[65536];
  __shared__ float xqs[64];
  short* Ah = (short*)pool;            // 16384 shorts
  short* Al = (short*)(pool + 32768);  // 16384 shorts
  float* sc = (float*)pool;            // 64 x 256 floats (aliased post-MFMA)

  const int t    = threadIdx.x;
  const int lane = t & 63;
  const int wv   = __builtin_amdgcn_readfirstlane(t >> 6);  // proto wave 0..7
  const int bx   = blockIdx.x;
  const int tile = bx >> 1, half = bx & 1;
  const int bbase = tile * 64;
  const int pl = lane & 31, h = lane >> 5;

  // ---- stage: 64 X rows f32 -> hi/lo bf16 fragments (8 lanes/row) ----
  {
    const int r  = t >> 3;
    const int sg = t & 7;
    const int rsh = r >> 5, rm = r & 31;
    const float* xrow = X + (size_t)(bbase + r) * ND;
    float ssq = 0.f;
    #pragma unroll
    for (int it = 0; it < 8; ++it) {
      const int c0 = it * 32 + sg * 4;
      const float4 v = *(const float4*)(xrow + c0);
      const float vv[4] = {v.x, v.y, v.z, v.w};
      short4v h4, l4;
      #pragma unroll
      for (int j = 0; j < 4; ++j) {
        ssq = fmaf(vv[j], vv[j], ssq);
        const unsigned short hh = f2bf_rn(vv[j]);
        h4[j] = (short)hh;
        l4[j] = (short)f2bf_rn(vv[j] - bf2f(hh));
      }
      const int step = c0 >> 4, hf = (c0 >> 3) & 1, j0 = c0 & 7;
      const int base = (((rsh * 16 + step) * 64) + (rm + 32 * hf)) * 8 + j0;
      *(short4v*)&Ah[base] = h4;
      *(short4v*)&Al[base] = l4;
    }
    ssq += __shfl_xor(ssq, 1, 64);
    ssq += __shfl_xor(ssq, 2, 64);
    ssq += __shfl_xor(ssq, 4, 64);
    if (sg == 0) xqs[r] = ssq;
  }
  __syncthreads();                     // B1: A-frags + xqs ready

  // per-lane prototype params (L2-resident)
  const int kp = half * 256 + wv * 32 + pl;
  const float wqk = WQ[kp], apk = AP[kp], g2k = G2[kp];
  const short8* bHc = (const short8*)PWH + (size_t)(half * 8 + wv) * 1024 + lane;
  const short8* bLc = (const short8*)PWL + (size_t)(half * 8 + wv) * 1024 + lane;

  float sreg0[16], sreg1[16];
  mfma_pass(Ah, Al, bHc, bLc, lane, 0, xqs, wqk, apk, g2k, sreg0);
  mfma_pass(Ah, Al, bHc, bLc, lane, 1, xqs, wqk, apk, g2k, sreg1);

  __syncthreads();                     // B2: all MFMA done, A-frags dead

  // write s-tile: sc[b][(p + 4b) & 255], p = wv*32+pl (conflict-free stores)
  {
    const int p = wv * 32 + pl;
    #pragma unroll
    for (int rg = 0; rg < 16; ++rg) {
      const int m  = (rg & 3) + 8 * (rg >> 2) + 4 * h;
      sc[m * 256 + ((p + 4 * m) & 255)] = sreg0[rg];
      const int b1 = m + 32;
      sc[b1 * 256 + ((p + 4 * b1) & 255)] = sreg1[rg];
    }
  }
  __syncthreads();                     // B3: s-tile complete

  // ---- combine: thread (b = lane, k-slice j3 = wv of 8x32) ----
  float Apc[OC];
  {
    const int j3 = wv;
    float sv[32];
    const int c0 = (j3 * 32 + 4 * lane);
    #pragma unroll
    for (int q = 0; q < 8; ++q)
      *(float4*)&sv[4 * q] = *(const float4*)&sc[lane * 256 + ((c0 + 4 * q) & 255)];

    const float* vt = VS + half * 256 + j3 * 32;   // wave-uniform -> s_load
    for (int c = 0; c < OC; ++c) {
      const float* vp = vt + (size_t)c * NP;
      float f8[8];
      #pragma unroll
      for (int j = 0; j < 8; ++j) f8[j] = fmaf(-sv[j], vp[j], 1.0f);
      #pragma unroll
      for (int j = 8; j < 32; ++j) f8[j & 7] *= fmaf(-sv[j], vp[j], 1.0f);
      Apc[c] = ((f8[0] * f8[1]) * (f8[2] * f8[3])) *
               ((f8[4] * f8[5]) * (f8[6] * f8[7]));
    }
  }
  __syncthreads();                     // B4: sc reads done; pool -> endgame

  // ---- endgame: reduce 8 k-slice partials -> PP[bx] (+ keep own in LDS) ----
  float* E    = (float*)pool;          // 8*21*64 = 10752 floats (42KB)
  float* Rloc = (float*)(pool + 43008);// 21*64 floats = own partial (5.25KB)
  #pragma unroll
  for (int c = 0; c < OC; ++c) E[(wv * OC + c) * 64 + lane] = Apc[c];
  __syncthreads();
  {
    const int b = t & 63, j = t >> 6;
    float* pp = PP + (size_t)bx * (OC * 64);
    for (int c = j; c < OC; c += 8) {
      float p = E[c * 64 + b];
      #pragma unroll
      for (int w = 1; w < 8; ++w) p *= E[(w * OC + c) * 64 + b];
      pp[c * 64 + b] = p;
      Rloc[c * 64 + b] = p;
    }
  }
  __threadfence();                     // release own PP stores (cross-XCD)
  __syncthreads();                     // all lanes fenced; Rloc complete

  // ---- pair handoff: second block to arrive merges + writes OUT ----
  int* bc = (int*)xqs;                 // xqs dead; reuse as broadcast slot
  if (t == 0) *bc = atomicAdd(&FLG[tile], 1);
  __syncthreads();
  if (*bc == 1) {
    __threadfence();                   // acquire partner's PP stores
    if (t < 64) {
      const float* q = PP + (size_t)(bx ^ 1) * (OC * 64) + t;
      float A2[OC];
      #pragma unroll
      for (int c = 0; c < OC; ++c) A2[c] = Rloc[c * 64 + t] * q[c * 64];
      const float Nv = A2[NCLS];
      float K = Nv;
      #pragma unroll
      for (int c = 0; c < NCLS; ++c) K += A2[c] - Nv;
      const float ik = 1.0f / K;
      float* o = OUT + ((size_t)bbase + t) * OC;
      #pragma unroll
      for (int c = 0; c < NCLS; ++c) o[c] = (A2[c] - Nv) * ik;
      o[NCLS] = Nv * ik;
    }
  }
}

// ---------------- fallback: R9 fused kernel (proven, used if ws < WS_BIG) ----------------
__global__ __launch_bounds__(512)
void evid_main(const float* __restrict__ X,
               const unsigned short* __restrict__ PWH, const unsigned short* __restrict__ PWL,
               const float* __restrict__ VS, const float* __restrict__ WQ,
               const float* __restrict__ AP, const float* __restrict__ G2,
               float* __restrict__ OUT)
{
  __shared__ __align__(16) short Ah[16384], Al[16384];
  __shared__ __align__(16) float sst[2][8192];
  __shared__ float xqs[64];

  const int t    = threadIdx.x;
  const int lane = t & 63;
  const int wv   = __builtin_amdgcn_readfirstlane(t >> 6);
  const int tile = blockIdx.x;
  const int bbase = tile * 64;
  const int sh = wv & 1, pg = wv >> 1;
  const int pl = lane & 31, h = lane >> 5;

  const short8* bH = (const short8*)PWH + (size_t)pg * 1024 + lane;
  const short8* bL = (const short8*)PWL + (size_t)pg * 1024 + lane;
  short8 wbh[4], wbl[4];
  #pragma unroll
  for (int p = 0; p < 4; ++p) { wbh[p] = bH[p * 64]; wbl[p] = bL[p * 64]; }

  {
    const int r  = t >> 3;
    const int sg = t & 7;
    const int rsh = r >> 5, rm = r & 31;
    const float* xrow = X + (size_t)(bbase + r) * ND;
    float ssq = 0.f;
    #pragma unroll
    for (int it = 0; it < 8; ++it) {
      const int c0 = it * 32 + sg * 4;
      const float4 v = *(const float4*)(xrow + c0);
      const float vv[4] = {v.x, v.y, v.z, v.w};
      short4v h4, l4;
      #pragma unroll
      for (int j = 0; j < 4; ++j) {
        ssq = fmaf(vv[j], vv[j], ssq);
        const unsigned short hh = f2bf_rn(vv[j]);
        h4[j] = (short)hh;
        l4[j] = (short)f2bf_rn(vv[j] - bf2f(hh));
      }
      const int step = c0 >> 4, hf = (c0 >> 3) & 1, j0 = c0 & 7;
      const int base = (((rsh * 16 + step) * 64) + (rm + 32 * hf)) * 8 + j0;
      *(short4v*)&Ah[base] = h4;
      *(short4v*)&Al[base] = l4;
    }
    ssq += __shfl_xor(ssq, 1, 64);
    ssq += __shfl_xor(ssq, 2, 64);
    ssq += __shfl_xor(ssq, 4, 64);
    if (sg == 0) xqs[r] = ssq;
  }
  __syncthreads();

  float xqv[16];
  #pragma unroll
  for (int rg = 0; rg < 16; ++rg)
    xqv[rg] = xqs[sh * 32 + (rg & 3) + 8 * (rg >> 2) + 4 * h];

  float Apc[OC];
  #pragma unroll
  for (int c = 0; c < OC; ++c) Apc[c] = 1.0f;

  #pragma unroll 1
  for (int chunk = 0; chunk < 4; ++chunk) {
    const int par = chunk & 1;
    float* sp = &sst[par][0];
    const int kp = chunk * 128 + pg * 32 + pl;
    const float wqk = WQ[kp], apk = AP[kp], g2k = G2[kp];

    f32x16 accA, accB, accC;
    #pragma unroll
    for (int i = 0; i < 16; ++i) { accA[i] = 0.f; accB[i] = 0.f; accC[i] = 0.f; }
    const short8* aH = (const short8*)Ah + (size_t)sh * 1024 + lane;
    const short8* aL = (const short8*)Al + (size_t)sh * 1024 + lane;
    #pragma unroll
    for (int step = 0; step < 16; ++step) {
      const short8 ah = aH[step * 64], al = aL[step * 64];
      const short8 bh = wbh[step & 3], bl = wbl[step & 3];
      if (step < 12) {
        wbh[step & 3] = bH[(step + 4) * 64];
        wbl[step & 3] = bL[(step + 4) * 64];
      }
      accA = __builtin_amdgcn_mfma_f32_32x32x16_bf16(ah, bh, accA, 0, 0, 0);
      accB = __builtin_amdgcn_mfma_f32_32x32x16_bf16(ah, bl, accB, 0, 0, 0);
      accC = __builtin_amdgcn_mfma_f32_32x32x16_bf16(al, bh, accC, 0, 0, 0);
    }

    #pragma unroll
    for (int rg = 0; rg < 16; ++rg) {
      const int   m  = (rg & 3) + 8 * (rg >> 2) + 4 * h;
      const int   b  = sh * 32 + m;
      const int   col = (pg * 32 + pl + 4 * m) & 127;
      const float dv = 0.5f * (wqk + xqv[rg]) - (accA[rg] + accB[rg] + accC[rg]);
      sp[b * 128 + col] = apk * __expf(-g2k * dv);
    }

    if (chunk < 3) {
      bH += 4096; bL += 4096;
      #pragma unroll
      for (int p = 0; p < 4; ++p) { wbh[p] = bH[p * 64]; wbl[p] = bL[p * 64]; }
    }

    __syncthreads();

    {
      const int kl = wv * 16;
      float sv[16];
      #pragma unroll
      for (int q = 0; q < 4; ++q) {
        const int col = (kl + 4 * (lane & 31) + 4 * q) & 127;
        *(float4*)&sv[4 * q] = *(const float4*)&sp[lane * 128 + col];
      }
      const float* vtab = VS + chunk * 128 + kl;
      for (int c = 0; c < OC; ++c) {
        const float* vp = vtab + (size_t)c * NP;
        float f[16];
        #pragma unroll
        for (int j = 0; j < 16; ++j) f[j] = fmaf(-sv[j], vp[j], 1.0f);
        const float p0 = (f[0] * f[1]) * (f[2] * f[3]);
        const float p1 = (f[4] * f[5]) * (f[6] * f[7]);
        const float p2 = (f[8] * f[9]) * (f[10] * f[11]);
        const float p3 = (f[12] * f[13]) * (f[14] * f[15]);
        Apc[c] *= (p0 * p1) * (p2 * p3);
      }
    }
  }

  __syncthreads();
  float* S = &sst[0][0];
  #pragma unroll
  for (int c = 0; c < OC; ++c) S[(wv * OC + c) * 64 + lane] = Apc[c];
  __syncthreads();
  float* R  = S + 11008;
  {
    const int b = t & 63, j = t >> 6;
    for (int c = j; c < OC; c += 8) {
      float p = S[c * 64 + b];
      #pragma unroll
      for (int w = 1; w < 8; ++w) p *= S[(w * OC + c) * 64 + b];
      R[c * 64 + b] = p;
    }
  }
  __syncthreads();
  float* kv = R + 1344;
  if (t < 64) {
    const float Nv = R[NCLS * 64 + t];
    float K = Nv;
    #pragma unroll
    for (int c = 0; c < NCLS; ++c) K += R[c * 64 + t] - Nv;
    kv[t] = 1.0f / K;
  }
  __syncthreads();
  for (int idx = t; idx < 64 * OC; idx += 512) {
    const int b = idx / OC, c = idx - b * OC;
    const float Nv = R[NCLS * 64 + b];
    const float ik = kv[b];
    OUT[(size_t)tile * 64 * OC + idx] = (c < NCLS) ? (R[c * 64 + b] - Nv) * ik : Nv * ik;
  }
}

extern "C" void kernel_launch(void* const* d_in, const int* in_sizes, int n_in,
                              void* d_out, int out_size, void* d_ws, size_t ws_size,
                              hipStream_t stream) {
  (void)in_sizes; (void)n_in; (void)out_size;
  const float* X     = (const float*)d_in[0];
  const float* Wm    = (const float*)d_in[1];
  const float* BETA  = (const float*)d_in[2];
  const float* ALPHA = (const float*)d_in[3];
  const float* GAMMA = (const float*)d_in[4];
  float* OUT = (float*)d_out;

  char* ws = (char*)d_ws;
  unsigned short* PWH = (unsigned short*)(ws + OFF_PWH);
  unsigned short* PWL = (unsigned short*)(ws + OFF_PWL);
  float* VS = (float*)(ws + OFF_VS);
  float* WQ = (float*)(ws + OFF_WQ);
  float* AP = (float*)(ws + OFF_AP);
  float* G2 = (float*)(ws + OFF_G2);
  int*   FLG = (int*)(ws + OFF_FLG);

  hipLaunchKernelGGL(prep, dim3(67), dim3(256), 0, stream,
                     Wm, BETA, ALPHA, GAMMA, PWH, PWL, WQ, VS, AP, G2, FLG);

  if (ws_size >= WS_BIG) {
    float* PP = (float*)(ws + OFF_PP);
    hipLaunchKernelGGL(gemm_comb, dim3(NBATCH/32), dim3(512), 0, stream,
                       X, PWH, PWL, VS, WQ, AP, G2, PP, FLG, OUT);
  } else {                             // proven fused fallback (R9)
    hipLaunchKernelGGL(evid_main, dim3(NBATCH/64), dim3(512), 0, stream,
                       X, PWH, PWL, VS, WQ, AP, G2, OUT);
  }
}

// Round 5
// 122.717 us; speedup vs baseline: 1.8440x; 1.8440x over previous
//
#include <hip/hip_runtime.h>
#include <math.h>

// EvidNets R18b: resubmit of R18 (round-4 bench died with "container failed
// twice" = infra, not a kernel failure; bounds re-audited: all LDS/global
// accesses in range, no divergent barriers, no cross-block waits).
// Two dispatches (prep + evid32), NO cross-block sync.
//   A_c(b) = prod_k (1 - s_kb*(1-U_kc)),  N(b) = prod_k (1 - s_kb)
//   out[b][c<20] = (A_c-N)/K, out[b][20] = N/K, K = sum_c A_c - 19N
//   s_kb = alphap_k * exp(-gamma_k^2*(0.5*(|W_k|^2+|x_b|^2) - W_k.x_b))
// R16/R17 post-mortem: VGPR=64 was NEVER the problem (no spill traffic:
// FETCH 18MB, WRITE 4.3MB; accs live in AGPRs, rocprof counts arch VGPRs
// only). The 162us came from the handoff tail: agent-scope __threadfence
// on non-coherent multi-XCD L2 = L2 writeback/invalidate per block,
// serializing -> all pipes idle (Mfma 3%, VALU 9%, HBM 2%). Lesson:
// NO cross-block fences on gfx950.
// R18: re-tile instead. Block = 32 samples x ALL 512 protos (512 blocks x
// 512 thr). Full per-sample product stays in-block -> normalize + OUT
// in-block. No PP/FLG/finish. Per-block MFMA unchanged (8 waves x 2
// passes x 48); pass1 takes the wave's 2nd proto-tile (same A, new B).
// LDS: A-frags 32KB -> alias sc[32][512]=64KB -> 2 blocks/CU preserved.
// Combine keeps wave-uniform VS (s_load): 8 slices x 64 protos, lanes
// 0..31 active. Costs: PW L2 traffic x2 (~+4us, overlapped), half-lane
// combine (+~3us). Gains: -finish dispatch -gap -PP round trip -half of
// X convert. NOTE: plain __launch_bounds__ (min-waves args spill, R4/R8).

#define NBATCH 16384
#define ND     256
#define NP     512
#define NCLS   20
#define OC     21

typedef short  short8  __attribute__((ext_vector_type(8)));
typedef short  short4v __attribute__((ext_vector_type(4)));
typedef unsigned short ushort8 __attribute__((ext_vector_type(8)));
typedef float  f32x16  __attribute__((ext_vector_type(16)));

// ---- workspace layout (bytes) ----
#define OFF_PWH 0u
#define OFF_PWL 262144u
#define OFF_VS  524288u                 // float VS[21][512] = 1-U (row 20 = 1)
#define OFF_WQ  567296u
#define OFF_AP  569344u
#define OFF_G2  571392u

__device__ __forceinline__ unsigned short f2bf_rn(float f) {
  unsigned int u = __float_as_uint(f);
  unsigned int r = (u + 0x7FFFu + ((u >> 16) & 1u)) >> 16;   // RNE (finite inputs)
  return (unsigned short)r;
}
__device__ __forceinline__ float bf2f(unsigned short h) {
  return __uint_as_float(((unsigned int)h) << 16);
}

// Combined prep: blocks 0..63 pack W[512][256] -> MFMA B-fragment order hi/lo
// bf16 + row sum-squares; blocks 64..65 build VS/AP/G2 tables.
// frag elem (tile,step,lane,j) = src[tile*32+(lane&31)][step*16+8*(lane>>5)+j]
__global__ __launch_bounds__(256)
void prep(const float* __restrict__ Wsrc, const float* __restrict__ BETA,
          const float* __restrict__ alpha, const float* __restrict__ gamma,
          unsigned short* __restrict__ dh, unsigned short* __restrict__ dl,
          float* __restrict__ sq, float* __restrict__ VS,
          float* __restrict__ AP, float* __restrict__ G2)
{
  const int bid = blockIdx.x;
  if (bid < 64) {                      // ---- pack W ----
    const int tid = bid * 256 + threadIdx.x;
    const int row = tid >> 5, seg = tid & 31;
    const float4* s4 = (const float4*)(Wsrc + (size_t)row * ND + seg * 8);
    const float4 a = s4[0], b = s4[1];
    const float v[8] = {a.x, a.y, a.z, a.w, b.x, b.y, b.z, b.w};
    ushort8 hv, lv;
    float ssq = 0.f;
    #pragma unroll
    for (int j = 0; j < 8; ++j) {
      ssq = fmaf(v[j], v[j], ssq);
      const unsigned short hh = f2bf_rn(v[j]);
      hv[j] = hh;
      lv[j] = f2bf_rn(v[j] - bf2f(hh));
    }
    const int tile = row >> 5, m = row & 31, step = seg >> 1, r = seg & 1;
    const size_t cidx = (size_t)(tile * 16 + step) * 64 + m + 32 * r;
    *(ushort8*)(dh + cidx * 8) = hv;
    *(ushort8*)(dl + cidx * 8) = lv;
    #pragma unroll
    for (int off = 1; off < 32; off <<= 1) ssq += __shfl_xor(ssq, off, 64);
    if (seg == 0) sq[row] = ssq;
  } else {                             // ---- scalar tables ----
    const int k = (bid - 64) * 256 + threadIdx.x;
    if (k >= NP) return;
    float bv[NCLS], bs = 0.f;
    #pragma unroll
    for (int c = 0; c < NCLS; ++c) { bv[c] = BETA[k * NCLS + c]; bs = fmaf(bv[c], bv[c], bs); }
    const float binv = 1.f / bs;
    #pragma unroll
    for (int c = 0; c < NCLS; ++c) VS[c * NP + k] = 1.f - bv[c] * bv[c] * binv;
    VS[NCLS * NP + k] = 1.f;
    AP[k] = 0.99f / (1.f + __expf(-alpha[k]));
    const float g = gamma[k];
    G2[k] = g * g;
  }
}

// One MFMA pass over the block's single 32-sample A-tile against one 32-proto
// B-tile: K=256, hi/lo split in TWO acc chains (accA = ah*bh; accB = ah*bl +
// al*bh), epilogue s -> sout[16]. Identical body to the proven R14 pass.
__device__ __forceinline__ void mfma_pass(
    const short* __restrict__ Ah, const short* __restrict__ Al,
    const short8* __restrict__ bHc, const short8* __restrict__ bLc,
    const int lane, const float* __restrict__ xqs,
    const float wqk, const float apk, const float g2k, float* __restrict__ sout)
{
  short8 wbh[4], wbl[4];
  #pragma unroll
  for (int p = 0; p < 4; ++p) { wbh[p] = bHc[p * 64]; wbl[p] = bLc[p * 64]; }

  f32x16 accA, accB;
  #pragma unroll
  for (int i = 0; i < 16; ++i) { accA[i] = 0.f; accB[i] = 0.f; }
  const short8* aH = (const short8*)Ah + lane;
  const short8* aL = (const short8*)Al + lane;
  #pragma unroll
  for (int step = 0; step < 16; ++step) {
    const short8 ah = aH[step * 64], al = aL[step * 64];
    const short8 bh = wbh[step & 3], bl = wbl[step & 3];
    if (step < 12) {
      wbh[step & 3] = bHc[(step + 4) * 64];
      wbl[step & 3] = bLc[(step + 4) * 64];
    }
    accA = __builtin_amdgcn_mfma_f32_32x32x16_bf16(ah, bh, accA, 0, 0, 0);
    accB = __builtin_amdgcn_mfma_f32_32x32x16_bf16(ah, bl, accB, 0, 0, 0);
    accB = __builtin_amdgcn_mfma_f32_32x32x16_bf16(al, bh, accB, 0, 0, 0);
  }
  // C/D: col(n)=lane&31 (proto), row(m)=(rg&3)+8*(rg>>2)+4*(lane>>5)
  const int h = lane >> 5;
  #pragma unroll
  for (int rg = 0; rg < 16; ++rg) {
    const int   m  = (rg & 3) + 8 * (rg >> 2) + 4 * h;
    const float dv = 0.5f * (wqk + xqs[m]) - (accA[rg] + accB[rg]);
    sout[rg] = apk * __expf(-g2k * dv);
  }
}

// ---- main: 512 blocks x 512 thr. Block bx: samples bx*32..+32, ALL 512
// protos. Wave wv owns proto-tiles (2wv, 2wv+1) = protos wv*64..+64.
// LDS pool: A-frags (32KB) during MFMA, then swizzled s-tile
// sc[b][(p+4b)&511] (64KB), then endgame E/R/kv. OUT written in-block. ----
__global__ __launch_bounds__(512)
void evid32(const float* __restrict__ X,
            const unsigned short* __restrict__ PWH, const unsigned short* __restrict__ PWL,
            const float* __restrict__ VS, const float* __restrict__ WQ,
            const float* __restrict__ AP, const float* __restrict__ G2,
            float* __restrict__ OUT)
{
  __shared__ __align__(16) char pool[65536];
  __shared__ float xqs[32];
  short* Ah = (short*)pool;            // 8192 shorts = 16KB
  short* Al = (short*)(pool + 16384);  // 8192 shorts = 16KB
  float* sc = (float*)pool;            // 32 x 512 floats = 64KB (post-MFMA)

  const int t    = threadIdx.x;
  const int lane = t & 63;
  const int wv   = __builtin_amdgcn_readfirstlane(t >> 6);  // wave 0..7
  const int bx   = blockIdx.x;
  const int bbase = bx * 32;
  const int pl = lane & 31, h = lane >> 5;

  // ---- stage: 32 X rows f32 -> hi/lo bf16 fragments (16 lanes/row, once) ----
  {
    const int r  = t >> 4;             // 0..31
    const int sg = t & 15;
    const float* xrow = X + (size_t)(bbase + r) * ND;
    float ssq = 0.f;
    #pragma unroll
    for (int it = 0; it < 4; ++it) {
      const int c0 = it * 64 + sg * 4;
      const float4 v = *(const float4*)(xrow + c0);
      const float vv[4] = {v.x, v.y, v.z, v.w};
      short4v h4, l4;
      #pragma unroll
      for (int j = 0; j < 4; ++j) {
        ssq = fmaf(vv[j], vv[j], ssq);
        const unsigned short hh = f2bf_rn(vv[j]);
        h4[j] = (short)hh;
        l4[j] = (short)f2bf_rn(vv[j] - bf2f(hh));
      }
      const int step = c0 >> 4, hf = (c0 >> 3) & 1, j0 = c0 & 7;
      const int base = (step * 64 + r + 32 * hf) * 8 + j0;
      *(short4v*)&Ah[base] = h4;
      *(short4v*)&Al[base] = l4;
    }
    ssq += __shfl_xor(ssq, 1, 64);
    ssq += __shfl_xor(ssq, 2, 64);
    ssq += __shfl_xor(ssq, 4, 64);
    ssq += __shfl_xor(ssq, 8, 64);
    if (sg == 0) xqs[r] = ssq;
  }
  __syncthreads();                     // B1: A-frags + xqs ready

  // per-lane prototype params for the wave's two proto-tiles (L2-resident)
  const int kp0 = wv * 64 + pl, kp1 = kp0 + 32;
  const float wq0 = WQ[kp0], ap0 = AP[kp0], g20 = G2[kp0];
  const float wq1 = WQ[kp1], ap1 = AP[kp1], g21 = G2[kp1];
  const short8* bH0 = (const short8*)PWH + (size_t)(2 * wv) * 1024 + lane;
  const short8* bL0 = (const short8*)PWL + (size_t)(2 * wv) * 1024 + lane;
  const short8* bH1 = bH0 + 1024;
  const short8* bL1 = bL0 + 1024;

  float sreg0[16], sreg1[16];
  mfma_pass(Ah, Al, bH0, bL0, lane, xqs, wq0, ap0, g20, sreg0);
  mfma_pass(Ah, Al, bH1, bL1, lane, xqs, wq1, ap1, g21, sreg1);

  __syncthreads();                     // B2: all MFMA done, A-frags dead

  // write s-tile: sc[b][(p + 4b) & 511] (conflict-free: 2-way max)
  {
    const int p0 = wv * 64 + pl, p1 = p0 + 32;
    #pragma unroll
    for (int rg = 0; rg < 16; ++rg) {
      const int m = (rg & 3) + 8 * (rg >> 2) + 4 * h;
      sc[m * 512 + ((p0 + 4 * m) & 511)] = sreg0[rg];
      sc[m * 512 + ((p1 + 4 * m) & 511)] = sreg1[rg];
    }
  }
  __syncthreads();                     // B3: s-tile complete

  // ---- combine: lanes 0..31 of wave wv, sample b = lane, slice = protos
  // wv*64..+64 in two 32-chunks. VS base wave-uniform -> s_load. ----
  float Apc[OC];
  #pragma unroll
  for (int c = 0; c < OC; ++c) Apc[c] = 1.0f;
  if (lane < 32) {
    const float* vt = VS + wv * 64;    // wave-uniform
    #pragma unroll
    for (int hh = 0; hh < 2; ++hh) {
      float sv[32];
      const int c0 = wv * 64 + hh * 32 + 4 * lane;
      #pragma unroll
      for (int q = 0; q < 8; ++q)
        *(float4*)&sv[4 * q] = *(const float4*)&sc[lane * 512 + ((c0 + 4 * q) & 511)];
      const float* vpb = vt + hh * 32;
      for (int c = 0; c < OC; ++c) {
        const float* vp = vpb + (size_t)c * NP;
        float f8[8];
        #pragma unroll
        for (int j = 0; j < 8; ++j) f8[j] = fmaf(-sv[j], vp[j], 1.0f);
        #pragma unroll
        for (int j = 8; j < 32; ++j) f8[j & 7] *= fmaf(-sv[j], vp[j], 1.0f);
        Apc[c] *= ((f8[0] * f8[1]) * (f8[2] * f8[3])) *
                  ((f8[4] * f8[5]) * (f8[6] * f8[7]));
      }
    }
  }
  __syncthreads();                     // B4: sc reads done; pool -> endgame

  // ---- endgame: reduce 8 wave-partials, normalize, store OUT in-block ----
  float* E  = (float*)pool;            // 8*21*32 = 5376 floats (21KB)
  float* R  = (float*)(pool + 22528);  // 21*32 floats
  float* kv = (float*)(pool + 25600);  // 32 floats
  if (lane < 32) {
    #pragma unroll
    for (int c = 0; c < OC; ++c) E[(wv * OC + c) * 32 + lane] = Apc[c];
  }
  __syncthreads();
  {
    const int b = t & 31, j = t >> 5;  // j = 0..15
    for (int c = j; c < OC; c += 16) {
      float p = E[c * 32 + b];
      #pragma unroll
      for (int w = 1; w < 8; ++w) p *= E[(w * OC + c) * 32 + b];
      R[c * 32 + b] = p;
    }
  }
  __syncthreads();
  if (t < 32) {
    const float Nv = R[NCLS * 32 + t];
    float K = Nv;
    #pragma unroll
    for (int c = 0; c < NCLS; ++c) K += R[c * 32 + t] - Nv;
    kv[t] = 1.0f / K;
  }
  __syncthreads();
  for (int idx = t; idx < 32 * OC; idx += 512) {
    const int b = idx / OC, c = idx - b * OC;
    const float Nv = R[NCLS * 32 + b];
    const float ik = kv[b];
    OUT[(size_t)bx * 32 * OC + idx] = (c < NCLS) ? (R[c * 32 + b] - Nv) * ik : Nv * ik;
  }
}

extern "C" void kernel_launch(void* const* d_in, const int* in_sizes, int n_in,
                              void* d_out, int out_size, void* d_ws, size_t ws_size,
                              hipStream_t stream) {
  (void)in_sizes; (void)n_in; (void)out_size; (void)ws_size;
  const float* X     = (const float*)d_in[0];
  const float* Wm    = (const float*)d_in[1];
  const float* BETA  = (const float*)d_in[2];
  const float* ALPHA = (const float*)d_in[3];
  const float* GAMMA = (const float*)d_in[4];
  float* OUT = (float*)d_out;

  char* ws = (char*)d_ws;
  unsigned short* PWH = (unsigned short*)(ws + OFF_PWH);
  unsigned short* PWL = (unsigned short*)(ws + OFF_PWL);
  float* VS = (float*)(ws + OFF_VS);
  float* WQ = (float*)(ws + OFF_WQ);
  float* AP = (float*)(ws + OFF_AP);
  float* G2 = (float*)(ws + OFF_G2);

  hipLaunchKernelGGL(prep, dim3(66), dim3(256), 0, stream,
                     Wm, BETA, ALPHA, GAMMA, PWH, PWL, WQ, VS, AP, G2);
  hipLaunchKernelGGL(evid32, dim3(NBATCH / 32), dim3(512), 0, stream,
                     X, PWH, PWL, VS, WQ, AP, G2, OUT);
}

// Round 6
// 104.678 us; speedup vs baseline: 2.1618x; 1.1723x over previous
//
#include <hip/hip_runtime.h>
#include <math.h>

// EvidNets R19: two dispatches (prep + evid64), self-sufficient 64-sample
// blocks, NO cross-block sync, NO finish kernel.
//   A_c(b) = prod_k (1 - s_kb*(1-U_kc)),  N(b) = prod_k (1 - s_kb)
//   out[b][c<20] = (A_c-N)/K, out[b][20] = N/K, K = sum_c A_c - 19N
//   s_kb = alphap_k * exp(-gamma_k^2*(0.5*(|W_k|^2+|x_b|^2) - W_k.x_b))
// R18b post-mortem (evid32 55.6us vs gemm_comb ~35-40): (1) half-lane combine
// doubled combine wave-cycles; (2) B-reuse lost (each wave 64KB distinct
// L2-cold B; round-0 re-used the B-tile across both sample-halves -> L1);
// (3) depth-4 ring (~130cy ahead) < L2 latency (~300cy).
// Timing model (consistent R0..R18): dur = 42 (harness 256MB fill, timed) +
// prep ~4 + gaps ~10 + main [+ finish ~5]. Need main <= 40 at 2 dispatches.
// R19: 256 blocks x 512 thr (1 block/CU). Block = 64 samples x ALL 512
// protos, two proto-half phases. Wave wv: tile wv (ph0), tile wv+8 (ph1);
// per phase 2 passes (sample-halves, SAME B-tile -> pass-2 L1 hits), write
// s-tile, barrier, round-0's verbatim full-lane combine (VS s_load stays
// wave-uniform), barrier, phase 1 overwrites s-tile. Full product in-block
// -> normalize + OUT in-block. LDS 128.3KB: A 64KB and sc 64KB coexist (no
// alias race); 1 block/CU anyway (grid==CUs). Registers free at 2 waves/EU
// (256 budget) -> B-ring depth 8 (~240cy prefetch). X read once (16.8MB).
// NOTE: plain __launch_bounds__ (min-waves args spilled, R4/R8).

#define NBATCH 16384
#define ND     256
#define NP     512
#define NCLS   20
#define OC     21

typedef short  short8  __attribute__((ext_vector_type(8)));
typedef short  short4v __attribute__((ext_vector_type(4)));
typedef unsigned short ushort8 __attribute__((ext_vector_type(8)));
typedef float  f32x16  __attribute__((ext_vector_type(16)));

// ---- workspace layout (bytes) ----
#define OFF_PWH 0u
#define OFF_PWL 262144u
#define OFF_VS  524288u                 // float VS[21][512] = 1-U (row 20 = 1)
#define OFF_WQ  567296u
#define OFF_AP  569344u
#define OFF_G2  571392u

__device__ __forceinline__ unsigned short f2bf_rn(float f) {
  unsigned int u = __float_as_uint(f);
  unsigned int r = (u + 0x7FFFu + ((u >> 16) & 1u)) >> 16;   // RNE (finite inputs)
  return (unsigned short)r;
}
__device__ __forceinline__ float bf2f(unsigned short h) {
  return __uint_as_float(((unsigned int)h) << 16);
}

// Combined prep: blocks 0..63 pack W[512][256] -> MFMA B-fragment order hi/lo
// bf16 + row sum-squares; blocks 64..65 build VS/AP/G2 tables.
// frag elem (tile,step,lane,j) = src[tile*32+(lane&31)][step*16+8*(lane>>5)+j]
__global__ __launch_bounds__(256)
void prep(const float* __restrict__ Wsrc, const float* __restrict__ BETA,
          const float* __restrict__ alpha, const float* __restrict__ gamma,
          unsigned short* __restrict__ dh, unsigned short* __restrict__ dl,
          float* __restrict__ sq, float* __restrict__ VS,
          float* __restrict__ AP, float* __restrict__ G2)
{
  const int bid = blockIdx.x;
  if (bid < 64) {                      // ---- pack W ----
    const int tid = bid * 256 + threadIdx.x;
    const int row = tid >> 5, seg = tid & 31;
    const float4* s4 = (const float4*)(Wsrc + (size_t)row * ND + seg * 8);
    const float4 a = s4[0], b = s4[1];
    const float v[8] = {a.x, a.y, a.z, a.w, b.x, b.y, b.z, b.w};
    ushort8 hv, lv;
    float ssq = 0.f;
    #pragma unroll
    for (int j = 0; j < 8; ++j) {
      ssq = fmaf(v[j], v[j], ssq);
      const unsigned short hh = f2bf_rn(v[j]);
      hv[j] = hh;
      lv[j] = f2bf_rn(v[j] - bf2f(hh));
    }
    const int tile = row >> 5, m = row & 31, step = seg >> 1, r = seg & 1;
    const size_t cidx = (size_t)(tile * 16 + step) * 64 + m + 32 * r;
    *(ushort8*)(dh + cidx * 8) = hv;
    *(ushort8*)(dl + cidx * 8) = lv;
    #pragma unroll
    for (int off = 1; off < 32; off <<= 1) ssq += __shfl_xor(ssq, off, 64);
    if (seg == 0) sq[row] = ssq;
  } else {                             // ---- scalar tables ----
    const int k = (bid - 64) * 256 + threadIdx.x;
    if (k >= NP) return;
    float bv[NCLS], bs = 0.f;
    #pragma unroll
    for (int c = 0; c < NCLS; ++c) { bv[c] = BETA[k * NCLS + c]; bs = fmaf(bv[c], bv[c], bs); }
    const float binv = 1.f / bs;
    #pragma unroll
    for (int c = 0; c < NCLS; ++c) VS[c * NP + k] = 1.f - bv[c] * bv[c] * binv;
    VS[NCLS * NP + k] = 1.f;
    AP[k] = 0.99f / (1.f + __expf(-alpha[k]));
    const float g = gamma[k];
    G2[k] = g * g;
  }
}

// One MFMA pass over sample-half sh: 32x32 tile, K=256, hi/lo split in TWO
// acc chains (accA = ah*bh; accB = ah*bl + al*bh), DEPTH-8 B ring (~240cy
// prefetch ~ L2 latency; regs free at 1 block/CU), epilogue s -> sout[16].
__device__ __forceinline__ void mfma_pass8(
    const short* __restrict__ Ah, const short* __restrict__ Al,
    const short8* __restrict__ bHc, const short8* __restrict__ bLc,
    const int lane, const int sh, const float* __restrict__ xqs,
    const float wqk, const float apk, const float g2k, float* __restrict__ sout)
{
  short8 wbh[8], wbl[8];
  #pragma unroll
  for (int p = 0; p < 8; ++p) { wbh[p] = bHc[p * 64]; wbl[p] = bLc[p * 64]; }

  f32x16 accA, accB;
  #pragma unroll
  for (int i = 0; i < 16; ++i) { accA[i] = 0.f; accB[i] = 0.f; }
  const short8* aH = (const short8*)Ah + (size_t)sh * 1024 + lane;
  const short8* aL = (const short8*)Al + (size_t)sh * 1024 + lane;
  #pragma unroll
  for (int step = 0; step < 16; ++step) {
    const short8 ah = aH[step * 64], al = aL[step * 64];
    const short8 bh = wbh[step & 7], bl = wbl[step & 7];
    if (step < 8) {
      wbh[step & 7] = bHc[(step + 8) * 64];
      wbl[step & 7] = bLc[(step + 8) * 64];
    }
    accA = __builtin_amdgcn_mfma_f32_32x32x16_bf16(ah, bh, accA, 0, 0, 0);
    accB = __builtin_amdgcn_mfma_f32_32x32x16_bf16(ah, bl, accB, 0, 0, 0);
    accB = __builtin_amdgcn_mfma_f32_32x32x16_bf16(al, bh, accB, 0, 0, 0);
  }
  // C/D: col(n)=lane&31 (proto), row(m)=(rg&3)+8*(rg>>2)+4*(lane>>5)
  const int h = lane >> 5;
  #pragma unroll
  for (int rg = 0; rg < 16; ++rg) {
    const int   m  = (rg & 3) + 8 * (rg >> 2) + 4 * h;
    const float dv = 0.5f * (wqk + xqs[sh * 32 + m]) - (accA[rg] + accB[rg]);
    sout[rg] = apk * __expf(-g2k * dv);
  }
}

// ---- main: 256 blocks x 512 thr (1 block/CU). Block bx: samples bx*64..+64,
// ALL 512 protos in two phases. LDS: A-frags 64KB [0,64K) + sc[64][256]
// 64KB [64K,128K) + xqs; endgame E/R/kv alias the A region (dead). ----
__global__ __launch_bounds__(512)
void evid64(const float* __restrict__ X,
            const unsigned short* __restrict__ PWH, const unsigned short* __restrict__ PWL,
            const float* __restrict__ VS, const float* __restrict__ WQ,
            const float* __restrict__ AP, const float* __restrict__ G2,
            float* __restrict__ OUT)
{
  __shared__ __align__(16) char pool[131072];
  __shared__ float xqs[64];
  short* Ah = (short*)pool;            // 16384 shorts = 32KB
  short* Al = (short*)(pool + 32768);  // 16384 shorts = 32KB
  float* sc = (float*)(pool + 65536);  // 64 x 256 floats = 64KB (per phase)

  const int t    = threadIdx.x;
  const int lane = t & 63;
  const int wv   = __builtin_amdgcn_readfirstlane(t >> 6);  // wave 0..7
  const int bx   = blockIdx.x;
  const int bbase = bx * 64;
  const int pl = lane & 31, h = lane >> 5;

  // ---- stage: 64 X rows f32 -> hi/lo bf16 fragments (8 lanes/row, once) ----
  {
    const int r  = t >> 3;
    const int sg = t & 7;
    const int rsh = r >> 5, rm = r & 31;
    const float* xrow = X + (size_t)(bbase + r) * ND;
    float ssq = 0.f;
    #pragma unroll
    for (int it = 0; it < 8; ++it) {
      const int c0 = it * 32 + sg * 4;
      const float4 v = *(const float4*)(xrow + c0);
      const float vv[4] = {v.x, v.y, v.z, v.w};
      short4v h4, l4;
      #pragma unroll
      for (int j = 0; j < 4; ++j) {
        ssq = fmaf(vv[j], vv[j], ssq);
        const unsigned short hh = f2bf_rn(vv[j]);
        h4[j] = (short)hh;
        l4[j] = (short)f2bf_rn(vv[j] - bf2f(hh));
      }
      const int step = c0 >> 4, hf = (c0 >> 3) & 1, j0 = c0 & 7;
      const int base = (((rsh * 16 + step) * 64) + (rm + 32 * hf)) * 8 + j0;
      *(short4v*)&Ah[base] = h4;
      *(short4v*)&Al[base] = l4;
    }
    ssq += __shfl_xor(ssq, 1, 64);
    ssq += __shfl_xor(ssq, 2, 64);
    ssq += __shfl_xor(ssq, 4, 64);
    if (sg == 0) xqs[r] = ssq;
  }
  __syncthreads();                     // B1: A-frags + xqs ready

  float Apc[OC];
  #pragma unroll
  for (int c = 0; c < OC; ++c) Apc[c] = 1.0f;

  // ---- two proto-half phases; wave wv owns tile (ph*8 + wv) ----
  #pragma unroll 1
  for (int ph = 0; ph < 2; ++ph) {
    if (ph == 1) __syncthreads();      // B3: ph0 sc reads done before rewrite

    const int kp = ph * 256 + wv * 32 + pl;           // global proto id
    const float wqk = WQ[kp], apk = AP[kp], g2k = G2[kp];
    const short8* bHc = (const short8*)PWH + (size_t)(ph * 8 + wv) * 1024 + lane;
    const short8* bLc = (const short8*)PWL + (size_t)(ph * 8 + wv) * 1024 + lane;
    const int p = wv * 32 + pl;                       // proto within phase

    #pragma unroll 1
    for (int sh = 0; sh < 2; ++sh) {   // same B-tile both halves -> L1 reuse
      float sreg[16];
      mfma_pass8(Ah, Al, bHc, bLc, lane, sh, xqs, wqk, apk, g2k, sreg);
      #pragma unroll
      for (int rg = 0; rg < 16; ++rg) {
        const int m = (rg & 3) + 8 * (rg >> 2) + 4 * h;
        const int b = sh * 32 + m;
        sc[b * 256 + ((p + 4 * b) & 255)] = sreg[rg];  // conflict-free swizzle
      }
    }
    __syncthreads();                   // B2/B4: s-tile (phase ph) complete

    // ---- combine (round-0 verbatim): thread b = lane, k-slice j3 = wv ----
    {
      float sv[32];
      const int c0 = (wv * 32 + 4 * lane);
      #pragma unroll
      for (int q = 0; q < 8; ++q)
        *(float4*)&sv[4 * q] = *(const float4*)&sc[lane * 256 + ((c0 + 4 * q) & 255)];

      const float* vt = VS + ph * 256 + wv * 32;      // wave-uniform -> s_load
      for (int c = 0; c < OC; ++c) {
        const float* vp = vt + (size_t)c * NP;
        float f8[8];
        #pragma unroll
        for (int j = 0; j < 8; ++j) f8[j] = fmaf(-sv[j], vp[j], 1.0f);
        #pragma unroll
        for (int j = 8; j < 32; ++j) f8[j & 7] *= fmaf(-sv[j], vp[j], 1.0f);
        Apc[c] *= ((f8[0] * f8[1]) * (f8[2] * f8[3])) *
                  ((f8[4] * f8[5]) * (f8[6] * f8[7]));
      }
    }
  }
  __syncthreads();                     // B5: all sc reads + A reads done

  // ---- endgame: reduce 8 wave-partials, normalize, store OUT in-block ----
  float* E  = (float*)pool;            // 8*21*64 floats = 42KB (A region, dead)
  float* R  = (float*)(pool + 43008);  // 21*64 floats
  float* kv = (float*)(pool + 48384);  // 64 floats
  #pragma unroll
  for (int c = 0; c < OC; ++c) E[(wv * OC + c) * 64 + lane] = Apc[c];
  __syncthreads();
  {
    const int b = t & 63, j = t >> 6;
    for (int c = j; c < OC; c += 8) {
      float p = E[c * 64 + b];
      #pragma unroll
      for (int w = 1; w < 8; ++w) p *= E[(w * OC + c) * 64 + b];
      R[c * 64 + b] = p;
    }
  }
  __syncthreads();
  if (t < 64) {
    const float Nv = R[NCLS * 64 + t];
    float K = Nv;
    #pragma unroll
    for (int c = 0; c < NCLS; ++c) K += R[c * 64 + t] - Nv;
    kv[t] = 1.0f / K;
  }
  __syncthreads();
  for (int idx = t; idx < 64 * OC; idx += 512) {
    const int b = idx / OC, c = idx - b * OC;
    const float Nv = R[NCLS * 64 + b];
    const float ik = kv[b];
    OUT[(size_t)bx * 64 * OC + idx] = (c < NCLS) ? (R[c * 64 + b] - Nv) * ik : Nv * ik;
  }
}

extern "C" void kernel_launch(void* const* d_in, const int* in_sizes, int n_in,
                              void* d_out, int out_size, void* d_ws, size_t ws_size,
                              hipStream_t stream) {
  (void)in_sizes; (void)n_in; (void)out_size; (void)ws_size;
  const float* X     = (const float*)d_in[0];
  const float* Wm    = (const float*)d_in[1];
  const float* BETA  = (const float*)d_in[2];
  const float* ALPHA = (const float*)d_in[3];
  const float* GAMMA = (const float*)d_in[4];
  float* OUT = (float*)d_out;

  char* ws = (char*)d_ws;
  unsigned short* PWH = (unsigned short*)(ws + OFF_PWH);
  unsigned short* PWL = (unsigned short*)(ws + OFF_PWL);
  float* VS = (float*)(ws + OFF_VS);
  float* WQ = (float*)(ws + OFF_WQ);
  float* AP = (float*)(ws + OFF_AP);
  float* G2 = (float*)(ws + OFF_G2);

  hipLaunchKernelGGL(prep, dim3(66), dim3(256), 0, stream,
                     Wm, BETA, ALPHA, GAMMA, PWH, PWL, WQ, VS, AP, G2);
  hipLaunchKernelGGL(evid64, dim3(NBATCH / 64), dim3(512), 0, stream,
                     X, PWH, PWL, VS, WQ, AP, G2, OUT);
}

// Round 7
// 100.777 us; speedup vs baseline: 2.2455x; 1.0387x over previous
//
#include <hip/hip_runtime.h>
#include <math.h>

// EvidNets R20: R19 with the inter-phase barriers REMOVED (waves free-run).
//   A_c(b) = prod_k (1 - s_kb*(1-U_kc)),  N(b) = prod_k (1 - s_kb)
//   out[b][c<20] = (A_c-N)/K, out[b][20] = N/K, K = sum_c A_c - 19N
//   s_kb = alphap_k * exp(-gamma_k^2*(0.5*(|W_k|^2+|x_b|^2) - W_k.x_b))
// R19 post-mortem: evid64 ~38us at 1 block/CU (2 waves/SIMD) vs gemm_comb
// ~30us at 2 blocks/CU. Compute is only ~7us/wave (MFMA 1536cy + combine
// ~5400cy VALU); the rest was lockstep: inter-phase __syncthreads forced all
// waves to do MFMA together then combine together -> matrix pipe idle during
// combine, VALU idle during MFMA, B-ring L2 latency exposed.
// KEY FACT (verified): wave wv writes s-tile band cols (wv*32+4b)&255 per
// row b, and wave wv's combine reads EXACTLY that band -> per-wave
// self-contained, bands disjoint across waves -> the inter-phase barriers
// were never needed for correctness. Removing them lets the 2 waves/SIMD
// run phase-shifted: one wave's combine overlaps the other's MFMA (m114
// MFMA/VALU co-schedule) and ph1 B-ring loads hide under ph0 combine
// (phase loop fully unrolled).
// Barriers kept: B1 (staging -> all waves read A) and B5 (endgame E aliases
// the A region other waves may still be reading) + endgame reduce barriers.
// NOTE: plain __launch_bounds__ (min-waves args spilled, R4/R8). Watch:
// if VGPR drops to 64 AND FETCH >> 18MB, the R15 spill heuristic returned.

#define NBATCH 16384
#define ND     256
#define NP     512
#define NCLS   20
#define OC     21

typedef short  short8  __attribute__((ext_vector_type(8)));
typedef short  short4v __attribute__((ext_vector_type(4)));
typedef unsigned short ushort8 __attribute__((ext_vector_type(8)));
typedef float  f32x16  __attribute__((ext_vector_type(16)));

// ---- workspace layout (bytes) ----
#define OFF_PWH 0u
#define OFF_PWL 262144u
#define OFF_VS  524288u                 // float VS[21][512] = 1-U (row 20 = 1)
#define OFF_WQ  567296u
#define OFF_AP  569344u
#define OFF_G2  571392u

__device__ __forceinline__ unsigned short f2bf_rn(float f) {
  unsigned int u = __float_as_uint(f);
  unsigned int r = (u + 0x7FFFu + ((u >> 16) & 1u)) >> 16;   // RNE (finite inputs)
  return (unsigned short)r;
}
__device__ __forceinline__ float bf2f(unsigned short h) {
  return __uint_as_float(((unsigned int)h) << 16);
}

// Combined prep: blocks 0..63 pack W[512][256] -> MFMA B-fragment order hi/lo
// bf16 + row sum-squares; blocks 64..65 build VS/AP/G2 tables.
// frag elem (tile,step,lane,j) = src[tile*32+(lane&31)][step*16+8*(lane>>5)+j]
__global__ __launch_bounds__(256)
void prep(const float* __restrict__ Wsrc, const float* __restrict__ BETA,
          const float* __restrict__ alpha, const float* __restrict__ gamma,
          unsigned short* __restrict__ dh, unsigned short* __restrict__ dl,
          float* __restrict__ sq, float* __restrict__ VS,
          float* __restrict__ AP, float* __restrict__ G2)
{
  const int bid = blockIdx.x;
  if (bid < 64) {                      // ---- pack W ----
    const int tid = bid * 256 + threadIdx.x;
    const int row = tid >> 5, seg = tid & 31;
    const float4* s4 = (const float4*)(Wsrc + (size_t)row * ND + seg * 8);
    const float4 a = s4[0], b = s4[1];
    const float v[8] = {a.x, a.y, a.z, a.w, b.x, b.y, b.z, b.w};
    ushort8 hv, lv;
    float ssq = 0.f;
    #pragma unroll
    for (int j = 0; j < 8; ++j) {
      ssq = fmaf(v[j], v[j], ssq);
      const unsigned short hh = f2bf_rn(v[j]);
      hv[j] = hh;
      lv[j] = f2bf_rn(v[j] - bf2f(hh));
    }
    const int tile = row >> 5, m = row & 31, step = seg >> 1, r = seg & 1;
    const size_t cidx = (size_t)(tile * 16 + step) * 64 + m + 32 * r;
    *(ushort8*)(dh + cidx * 8) = hv;
    *(ushort8*)(dl + cidx * 8) = lv;
    #pragma unroll
    for (int off = 1; off < 32; off <<= 1) ssq += __shfl_xor(ssq, off, 64);
    if (seg == 0) sq[row] = ssq;
  } else {                             // ---- scalar tables ----
    const int k = (bid - 64) * 256 + threadIdx.x;
    if (k >= NP) return;
    float bv[NCLS], bs = 0.f;
    #pragma unroll
    for (int c = 0; c < NCLS; ++c) { bv[c] = BETA[k * NCLS + c]; bs = fmaf(bv[c], bv[c], bs); }
    const float binv = 1.f / bs;
    #pragma unroll
    for (int c = 0; c < NCLS; ++c) VS[c * NP + k] = 1.f - bv[c] * bv[c] * binv;
    VS[NCLS * NP + k] = 1.f;
    AP[k] = 0.99f / (1.f + __expf(-alpha[k]));
    const float g = gamma[k];
    G2[k] = g * g;
  }
}

// One MFMA pass over sample-half sh: 32x32 tile, K=256, hi/lo split in TWO
// acc chains (accA = ah*bh; accB = ah*bl + al*bh), DEPTH-8 B ring (~240cy
// prefetch ~ L2 latency; regs free at 1 block/CU), epilogue s -> sout[16].
__device__ __forceinline__ void mfma_pass8(
    const short* __restrict__ Ah, const short* __restrict__ Al,
    const short8* __restrict__ bHc, const short8* __restrict__ bLc,
    const int lane, const int sh, const float* __restrict__ xqs,
    const float wqk, const float apk, const float g2k, float* __restrict__ sout)
{
  short8 wbh[8], wbl[8];
  #pragma unroll
  for (int p = 0; p < 8; ++p) { wbh[p] = bHc[p * 64]; wbl[p] = bLc[p * 64]; }

  f32x16 accA, accB;
  #pragma unroll
  for (int i = 0; i < 16; ++i) { accA[i] = 0.f; accB[i] = 0.f; }
  const short8* aH = (const short8*)Ah + (size_t)sh * 1024 + lane;
  const short8* aL = (const short8*)Al + (size_t)sh * 1024 + lane;
  #pragma unroll
  for (int step = 0; step < 16; ++step) {
    const short8 ah = aH[step * 64], al = aL[step * 64];
    const short8 bh = wbh[step & 7], bl = wbl[step & 7];
    if (step < 8) {
      wbh[step & 7] = bHc[(step + 8) * 64];
      wbl[step & 7] = bLc[(step + 8) * 64];
    }
    accA = __builtin_amdgcn_mfma_f32_32x32x16_bf16(ah, bh, accA, 0, 0, 0);
    accB = __builtin_amdgcn_mfma_f32_32x32x16_bf16(ah, bl, accB, 0, 0, 0);
    accB = __builtin_amdgcn_mfma_f32_32x32x16_bf16(al, bh, accB, 0, 0, 0);
  }
  // C/D: col(n)=lane&31 (proto), row(m)=(rg&3)+8*(rg>>2)+4*(lane>>5)
  const int h = lane >> 5;
  #pragma unroll
  for (int rg = 0; rg < 16; ++rg) {
    const int   m  = (rg & 3) + 8 * (rg >> 2) + 4 * h;
    const float dv = 0.5f * (wqk + xqs[sh * 32 + m]) - (accA[rg] + accB[rg]);
    sout[rg] = apk * __expf(-g2k * dv);
  }
}

// ---- main: 256 blocks x 512 thr (1 block/CU). Block bx: samples bx*64..+64,
// ALL 512 protos in two phases, NO inter-phase barriers (per-wave
// self-contained s-tile bands). LDS: A-frags 64KB [0,64K) + sc[64][256]
// 64KB [64K,128K) + xqs; endgame E/R/kv alias the A region after B5. ----
__global__ __launch_bounds__(512)
void evid64(const float* __restrict__ X,
            const unsigned short* __restrict__ PWH, const unsigned short* __restrict__ PWL,
            const float* __restrict__ VS, const float* __restrict__ WQ,
            const float* __restrict__ AP, const float* __restrict__ G2,
            float* __restrict__ OUT)
{
  __shared__ __align__(16) char pool[131072];
  __shared__ float xqs[64];
  short* Ah = (short*)pool;            // 16384 shorts = 32KB
  short* Al = (short*)(pool + 32768);  // 16384 shorts = 32KB
  float* sc = (float*)(pool + 65536);  // 64 x 256 floats = 64KB (per phase)

  const int t    = threadIdx.x;
  const int lane = t & 63;
  const int wv   = __builtin_amdgcn_readfirstlane(t >> 6);  // wave 0..7
  const int bx   = blockIdx.x;
  const int bbase = bx * 64;
  const int pl = lane & 31, h = lane >> 5;

  // ---- stage: 64 X rows f32 -> hi/lo bf16 fragments (8 lanes/row, once) ----
  {
    const int r  = t >> 3;
    const int sg = t & 7;
    const int rsh = r >> 5, rm = r & 31;
    const float* xrow = X + (size_t)(bbase + r) * ND;
    float ssq = 0.f;
    #pragma unroll
    for (int it = 0; it < 8; ++it) {
      const int c0 = it * 32 + sg * 4;
      const float4 v = *(const float4*)(xrow + c0);
      const float vv[4] = {v.x, v.y, v.z, v.w};
      short4v h4, l4;
      #pragma unroll
      for (int j = 0; j < 4; ++j) {
        ssq = fmaf(vv[j], vv[j], ssq);
        const unsigned short hh = f2bf_rn(vv[j]);
        h4[j] = (short)hh;
        l4[j] = (short)f2bf_rn(vv[j] - bf2f(hh));
      }
      const int step = c0 >> 4, hf = (c0 >> 3) & 1, j0 = c0 & 7;
      const int base = (((rsh * 16 + step) * 64) + (rm + 32 * hf)) * 8 + j0;
      *(short4v*)&Ah[base] = h4;
      *(short4v*)&Al[base] = l4;
    }
    ssq += __shfl_xor(ssq, 1, 64);
    ssq += __shfl_xor(ssq, 2, 64);
    ssq += __shfl_xor(ssq, 4, 64);
    if (sg == 0) xqs[r] = ssq;
  }
  __syncthreads();                     // B1: A-frags + xqs ready

  float Apc[OC];
  #pragma unroll
  for (int c = 0; c < OC; ++c) Apc[c] = 1.0f;

  // ---- two proto-half phases; wave wv owns tile (ph*8 + wv). NO barriers:
  // each wave's s-band is written and read only by itself; waves free-run
  // so one wave's combine (VALU) overlaps another's MFMA + B-ring L2. ----
  #pragma unroll
  for (int ph = 0; ph < 2; ++ph) {
    const int kp = ph * 256 + wv * 32 + pl;           // global proto id
    const float wqk = WQ[kp], apk = AP[kp], g2k = G2[kp];
    const short8* bHc = (const short8*)PWH + (size_t)(ph * 8 + wv) * 1024 + lane;
    const short8* bLc = (const short8*)PWL + (size_t)(ph * 8 + wv) * 1024 + lane;
    const int p = wv * 32 + pl;                       // proto within phase

    #pragma unroll
    for (int sh = 0; sh < 2; ++sh) {   // same B-tile both halves -> L1 reuse
      float sreg[16];
      mfma_pass8(Ah, Al, bHc, bLc, lane, sh, xqs, wqk, apk, g2k, sreg);
      #pragma unroll
      for (int rg = 0; rg < 16; ++rg) {
        const int m = (rg & 3) + 8 * (rg >> 2) + 4 * h;
        const int b = sh * 32 + m;
        sc[b * 256 + ((p + 4 * b) & 255)] = sreg[rg];  // own band only
      }
    }
    // no barrier: within-wave LDS write->read ordering via lgkmcnt

    // ---- combine: thread b = lane, own k-slice (wv). VS wave-uniform. ----
    {
      float sv[32];
      const int c0 = (wv * 32 + 4 * lane);
      #pragma unroll
      for (int q = 0; q < 8; ++q)
        *(float4*)&sv[4 * q] = *(const float4*)&sc[lane * 256 + ((c0 + 4 * q) & 255)];

      const float* vt = VS + ph * 256 + wv * 32;      // wave-uniform -> s_load
      for (int c = 0; c < OC; ++c) {
        const float* vp = vt + (size_t)c * NP;
        float f8[8];
        #pragma unroll
        for (int j = 0; j < 8; ++j) f8[j] = fmaf(-sv[j], vp[j], 1.0f);
        #pragma unroll
        for (int j = 8; j < 32; ++j) f8[j & 7] *= fmaf(-sv[j], vp[j], 1.0f);
        Apc[c] *= ((f8[0] * f8[1]) * (f8[2] * f8[3])) *
                  ((f8[4] * f8[5]) * (f8[6] * f8[7]));
      }
    }
  }
  __syncthreads();                     // B5: all waves done with A/sc regions

  // ---- endgame: reduce 8 wave-partials, normalize, store OUT in-block ----
  float* E  = (float*)pool;            // 8*21*64 floats = 42KB (A region, dead)
  float* R  = (float*)(pool + 43008);  // 21*64 floats
  float* kv = (float*)(pool + 48384);  // 64 floats
  #pragma unroll
  for (int c = 0; c < OC; ++c) E[(wv * OC + c) * 64 + lane] = Apc[c];
  __syncthreads();
  {
    const int b = t & 63, j = t >> 6;
    for (int c = j; c < OC; c += 8) {
      float p = E[c * 64 + b];
      #pragma unroll
      for (int w = 1; w < 8; ++w) p *= E[(w * OC + c) * 64 + b];
      R[c * 64 + b] = p;
    }
  }
  __syncthreads();
  if (t < 64) {
    const float Nv = R[NCLS * 64 + t];
    float K = Nv;
    #pragma unroll
    for (int c = 0; c < NCLS; ++c) K += R[c * 64 + t] - Nv;
    kv[t] = 1.0f / K;
  }
  __syncthreads();
  for (int idx = t; idx < 64 * OC; idx += 512) {
    const int b = idx / OC, c = idx - b * OC;
    const float Nv = R[NCLS * 64 + b];
    const float ik = kv[b];
    OUT[(size_t)bx * 64 * OC + idx] = (c < NCLS) ? (R[c * 64 + b] - Nv) * ik : Nv * ik;
  }
}

extern "C" void kernel_launch(void* const* d_in, const int* in_sizes, int n_in,
                              void* d_out, int out_size, void* d_ws, size_t ws_size,
                              hipStream_t stream) {
  (void)in_sizes; (void)n_in; (void)out_size; (void)ws_size;
  const float* X     = (const float*)d_in[0];
  const float* Wm    = (const float*)d_in[1];
  const float* BETA  = (const float*)d_in[2];
  const float* ALPHA = (const float*)d_in[3];
  const float* GAMMA = (const float*)d_in[4];
  float* OUT = (float*)d_out;

  char* ws = (char*)d_ws;
  unsigned short* PWH = (unsigned short*)(ws + OFF_PWH);
  unsigned short* PWL = (unsigned short*)(ws + OFF_PWL);
  float* VS = (float*)(ws + OFF_VS);
  float* WQ = (float*)(ws + OFF_WQ);
  float* AP = (float*)(ws + OFF_AP);
  float* G2 = (float*)(ws + OFF_G2);

  hipLaunchKernelGGL(prep, dim3(66), dim3(256), 0, stream,
                     Wm, BETA, ALPHA, GAMMA, PWH, PWL, WQ, VS, AP, G2);
  hipLaunchKernelGGL(evid64, dim3(NBATCH / 64), dim3(512), 0, stream,
                     X, PWH, PWL, VS, WQ, AP, G2, OUT);
}

// Round 8
// 97.901 us; speedup vs baseline: 2.3114x; 1.0294x over previous
//
#include <hip/hip_runtime.h>
#include <math.h>

// EvidNets R21: R20 + per-wave VS slice staged into LDS (kills combine s_load
// stalls).
//   A_c(b) = prod_k (1 - s_kb*(1-U_kc)),  N(b) = prod_k (1 - s_kb)
//   out[b][c<20] = (A_c-N)/K, out[b][20] = N/K, K = sum_c A_c - 19N
//   s_kb = alphap_k * exp(-gamma_k^2*(0.5*(|W_k|^2+|x_b|^2) - W_k.x_b))
// R20 post-mortem: evid64 48us but VALU work is only ~14.4K cyc/SIMD (6us)
// and MFMA 3K cyc -> 5x stall dilation (VALUBusy 18%, MfmaUtil 10%). Theory:
// combine reads VS via 672 wave-uniform s_loads per wave-phase INSIDE the
// product chain; ~300cy SMEM latency per class-chunk, both SIMD-waves issue
// the same pattern simultaneously -> ~12-15K stall cyc/wave. Fix: each wave
// bulk-loads its 20x32 VS slice (row 20 == 1.0 handled inline) into a
// PRIVATE LDS region at phase start (10 vector loads/lane, issued before the
// MFMA passes -> hidden under ~3000cy of MFMA), combine reads broadcast
// ds_read. No new barriers (per-wave private slice; same-wave lgkmcnt
// ordering). LDS 148.6KB, still 1 block/CU. c-loop unroll 4 for ILP.
// NOTE: plain __launch_bounds__ (min-waves args spilled, R4/R8). Watch:
// VGPR ~130-160 expected; if FETCH >> 10.7MB, spill heuristic returned.

#define NBATCH 16384
#define ND     256
#define NP     512
#define NCLS   20
#define OC     21

typedef short  short8  __attribute__((ext_vector_type(8)));
typedef short  short4v __attribute__((ext_vector_type(4)));
typedef unsigned short ushort8 __attribute__((ext_vector_type(8)));
typedef float  f32x16  __attribute__((ext_vector_type(16)));

// ---- workspace layout (bytes) ----
#define OFF_PWH 0u
#define OFF_PWL 262144u
#define OFF_VS  524288u                 // float VS[21][512] = 1-U (row 20 = 1)
#define OFF_WQ  567296u
#define OFF_AP  569344u
#define OFF_G2  571392u

__device__ __forceinline__ unsigned short f2bf_rn(float f) {
  unsigned int u = __float_as_uint(f);
  unsigned int r = (u + 0x7FFFu + ((u >> 16) & 1u)) >> 16;   // RNE (finite inputs)
  return (unsigned short)r;
}
__device__ __forceinline__ float bf2f(unsigned short h) {
  return __uint_as_float(((unsigned int)h) << 16);
}

// Combined prep: blocks 0..63 pack W[512][256] -> MFMA B-fragment order hi/lo
// bf16 + row sum-squares; blocks 64..65 build VS/AP/G2 tables.
// frag elem (tile,step,lane,j) = src[tile*32+(lane&31)][step*16+8*(lane>>5)+j]
__global__ __launch_bounds__(256)
void prep(const float* __restrict__ Wsrc, const float* __restrict__ BETA,
          const float* __restrict__ alpha, const float* __restrict__ gamma,
          unsigned short* __restrict__ dh, unsigned short* __restrict__ dl,
          float* __restrict__ sq, float* __restrict__ VS,
          float* __restrict__ AP, float* __restrict__ G2)
{
  const int bid = blockIdx.x;
  if (bid < 64) {                      // ---- pack W ----
    const int tid = bid * 256 + threadIdx.x;
    const int row = tid >> 5, seg = tid & 31;
    const float4* s4 = (const float4*)(Wsrc + (size_t)row * ND + seg * 8);
    const float4 a = s4[0], b = s4[1];
    const float v[8] = {a.x, a.y, a.z, a.w, b.x, b.y, b.z, b.w};
    ushort8 hv, lv;
    float ssq = 0.f;
    #pragma unroll
    for (int j = 0; j < 8; ++j) {
      ssq = fmaf(v[j], v[j], ssq);
      const unsigned short hh = f2bf_rn(v[j]);
      hv[j] = hh;
      lv[j] = f2bf_rn(v[j] - bf2f(hh));
    }
    const int tile = row >> 5, m = row & 31, step = seg >> 1, r = seg & 1;
    const size_t cidx = (size_t)(tile * 16 + step) * 64 + m + 32 * r;
    *(ushort8*)(dh + cidx * 8) = hv;
    *(ushort8*)(dl + cidx * 8) = lv;
    #pragma unroll
    for (int off = 1; off < 32; off <<= 1) ssq += __shfl_xor(ssq, off, 64);
    if (seg == 0) sq[row] = ssq;
  } else {                             // ---- scalar tables ----
    const int k = (bid - 64) * 256 + threadIdx.x;
    if (k >= NP) return;
    float bv[NCLS], bs = 0.f;
    #pragma unroll
    for (int c = 0; c < NCLS; ++c) { bv[c] = BETA[k * NCLS + c]; bs = fmaf(bv[c], bv[c], bs); }
    const float binv = 1.f / bs;
    #pragma unroll
    for (int c = 0; c < NCLS; ++c) VS[c * NP + k] = 1.f - bv[c] * bv[c] * binv;
    VS[NCLS * NP + k] = 1.f;
    AP[k] = 0.99f / (1.f + __expf(-alpha[k]));
    const float g = gamma[k];
    G2[k] = g * g;
  }
}

// One MFMA pass over sample-half sh: 32x32 tile, K=256, hi/lo split in TWO
// acc chains (accA = ah*bh; accB = ah*bl + al*bh), DEPTH-8 B ring, epilogue
// s -> sout[16].
__device__ __forceinline__ void mfma_pass8(
    const short* __restrict__ Ah, const short* __restrict__ Al,
    const short8* __restrict__ bHc, const short8* __restrict__ bLc,
    const int lane, const int sh, const float* __restrict__ xqs,
    const float wqk, const float apk, const float g2k, float* __restrict__ sout)
{
  short8 wbh[8], wbl[8];
  #pragma unroll
  for (int p = 0; p < 8; ++p) { wbh[p] = bHc[p * 64]; wbl[p] = bLc[p * 64]; }

  f32x16 accA, accB;
  #pragma unroll
  for (int i = 0; i < 16; ++i) { accA[i] = 0.f; accB[i] = 0.f; }
  const short8* aH = (const short8*)Ah + (size_t)sh * 1024 + lane;
  const short8* aL = (const short8*)Al + (size_t)sh * 1024 + lane;
  #pragma unroll
  for (int step = 0; step < 16; ++step) {
    const short8 ah = aH[step * 64], al = aL[step * 64];
    const short8 bh = wbh[step & 7], bl = wbl[step & 7];
    if (step < 8) {
      wbh[step & 7] = bHc[(step + 8) * 64];
      wbl[step & 7] = bLc[(step + 8) * 64];
    }
    accA = __builtin_amdgcn_mfma_f32_32x32x16_bf16(ah, bh, accA, 0, 0, 0);
    accB = __builtin_amdgcn_mfma_f32_32x32x16_bf16(ah, bl, accB, 0, 0, 0);
    accB = __builtin_amdgcn_mfma_f32_32x32x16_bf16(al, bh, accB, 0, 0, 0);
  }
  // C/D: col(n)=lane&31 (proto), row(m)=(rg&3)+8*(rg>>2)+4*(lane>>5)
  const int h = lane >> 5;
  #pragma unroll
  for (int rg = 0; rg < 16; ++rg) {
    const int   m  = (rg & 3) + 8 * (rg >> 2) + 4 * h;
    const float dv = 0.5f * (wqk + xqs[sh * 32 + m]) - (accA[rg] + accB[rg]);
    sout[rg] = apk * __expf(-g2k * dv);
  }
}

// ---- main: 256 blocks x 512 thr (1 block/CU). Block bx: samples bx*64..+64,
// ALL 512 protos in two phases, NO inter-phase barriers (per-wave
// self-contained s-tile bands + private VS slices). LDS: A-frags 64KB +
// sc[64][256] 64KB + vsl[8][20][32] 20KB + xqs; endgame aliases A after B5. ----
__global__ __launch_bounds__(512)
void evid64(const float* __restrict__ X,
            const unsigned short* __restrict__ PWH, const unsigned short* __restrict__ PWL,
            const float* __restrict__ VS, const float* __restrict__ WQ,
            const float* __restrict__ AP, const float* __restrict__ G2,
            float* __restrict__ OUT)
{
  __shared__ __align__(16) char pool[131072];
  __shared__ float vsl[8 * NCLS * 32];   // per-wave private VS slices (20KB)
  __shared__ float xqs[64];
  short* Ah = (short*)pool;            // 16384 shorts = 32KB
  short* Al = (short*)(pool + 32768);  // 16384 shorts = 32KB
  float* sc = (float*)(pool + 65536);  // 64 x 256 floats = 64KB (per phase)

  const int t    = threadIdx.x;
  const int lane = t & 63;
  const int wv   = __builtin_amdgcn_readfirstlane(t >> 6);  // wave 0..7
  const int bx   = blockIdx.x;
  const int bbase = bx * 64;
  const int pl = lane & 31, h = lane >> 5;

  // ---- stage: 64 X rows f32 -> hi/lo bf16 fragments (8 lanes/row, once) ----
  {
    const int r  = t >> 3;
    const int sg = t & 7;
    const int rsh = r >> 5, rm = r & 31;
    const float* xrow = X + (size_t)(bbase + r) * ND;
    float ssq = 0.f;
    #pragma unroll
    for (int it = 0; it < 8; ++it) {
      const int c0 = it * 32 + sg * 4;
      const float4 v = *(const float4*)(xrow + c0);
      const float vv[4] = {v.x, v.y, v.z, v.w};
      short4v h4, l4;
      #pragma unroll
      for (int j = 0; j < 4; ++j) {
        ssq = fmaf(vv[j], vv[j], ssq);
        const unsigned short hh = f2bf_rn(vv[j]);
        h4[j] = (short)hh;
        l4[j] = (short)f2bf_rn(vv[j] - bf2f(hh));
      }
      const int step = c0 >> 4, hf = (c0 >> 3) & 1, j0 = c0 & 7;
      const int base = (((rsh * 16 + step) * 64) + (rm + 32 * hf)) * 8 + j0;
      *(short4v*)&Ah[base] = h4;
      *(short4v*)&Al[base] = l4;
    }
    ssq += __shfl_xor(ssq, 1, 64);
    ssq += __shfl_xor(ssq, 2, 64);
    ssq += __shfl_xor(ssq, 4, 64);
    if (sg == 0) xqs[r] = ssq;
  }
  __syncthreads();                     // B1: A-frags + xqs ready

  float Apc[OC];
  #pragma unroll
  for (int c = 0; c < OC; ++c) Apc[c] = 1.0f;

  float* vw = vsl + wv * (NCLS * 32);  // this wave's private VS slice

  // ---- two proto-half phases; wave wv owns tile (ph*8 + wv). NO barriers:
  // s-band and VS slice are wave-private; waves free-run so one wave's
  // combine (VALU) overlaps another's MFMA + B-ring L2. ----
  #pragma unroll
  for (int ph = 0; ph < 2; ++ph) {
    // stage this wave's VS slice EARLY (hidden under the MFMA passes).
    // Single buffer is safe across phases: same-wave WAR via lgkmcnt.
    {
      const float* vg = VS + ph * 256 + wv * 32;     // + c*NP
      #pragma unroll
      for (int i = 0; i < 10; ++i) {
        const int idx = i * 64 + lane;               // 0..639 = c*32+j
        vw[idx] = vg[(idx >> 5) * NP + (idx & 31)];
      }
    }

    const int kp = ph * 256 + wv * 32 + pl;           // global proto id
    const float wqk = WQ[kp], apk = AP[kp], g2k = G2[kp];
    const short8* bHc = (const short8*)PWH + (size_t)(ph * 8 + wv) * 1024 + lane;
    const short8* bLc = (const short8*)PWL + (size_t)(ph * 8 + wv) * 1024 + lane;
    const int p = wv * 32 + pl;                       // proto within phase

    #pragma unroll
    for (int sh = 0; sh < 2; ++sh) {   // same B-tile both halves -> L1 reuse
      float sreg[16];
      mfma_pass8(Ah, Al, bHc, bLc, lane, sh, xqs, wqk, apk, g2k, sreg);
      #pragma unroll
      for (int rg = 0; rg < 16; ++rg) {
        const int m = (rg & 3) + 8 * (rg >> 2) + 4 * h;
        const int b = sh * 32 + m;
        sc[b * 256 + ((p + 4 * b) & 255)] = sreg[rg];  // own band only
      }
    }
    // no barrier: within-wave LDS write->read ordering via lgkmcnt

    // ---- combine: thread b = lane, own k-slice (wv). VS from LDS. ----
    {
      float sv[32];
      const int c0 = (wv * 32 + 4 * lane);
      #pragma unroll
      for (int q = 0; q < 8; ++q)
        *(float4*)&sv[4 * q] = *(const float4*)&sc[lane * 256 + ((c0 + 4 * q) & 255)];

      #pragma unroll 4
      for (int c = 0; c < NCLS; ++c) {
        const float* vp = vw + c * 32;                // LDS broadcast reads
        float f8[8];
        #pragma unroll
        for (int j = 0; j < 8; ++j) f8[j] = fmaf(-sv[j], vp[j], 1.0f);
        #pragma unroll
        for (int j = 8; j < 32; ++j) f8[j & 7] *= fmaf(-sv[j], vp[j], 1.0f);
        Apc[c] *= ((f8[0] * f8[1]) * (f8[2] * f8[3])) *
                  ((f8[4] * f8[5]) * (f8[6] * f8[7]));
      }
      // c = 20: VS row == 1.0 -> f = 1 - s
      {
        float f8[8];
        #pragma unroll
        for (int j = 0; j < 8; ++j) f8[j] = 1.0f - sv[j];
        #pragma unroll
        for (int j = 8; j < 32; ++j) f8[j & 7] *= (1.0f - sv[j]);
        Apc[NCLS] *= ((f8[0] * f8[1]) * (f8[2] * f8[3])) *
                     ((f8[4] * f8[5]) * (f8[6] * f8[7]));
      }
    }
  }
  __syncthreads();                     // B5: all waves done with A/sc regions

  // ---- endgame: reduce 8 wave-partials, normalize, store OUT in-block ----
  float* E  = (float*)pool;            // 8*21*64 floats = 42KB (A region, dead)
  float* R  = (float*)(pool + 43008);  // 21*64 floats
  float* kv = (float*)(pool + 48384);  // 64 floats
  #pragma unroll
  for (int c = 0; c < OC; ++c) E[(wv * OC + c) * 64 + lane] = Apc[c];
  __syncthreads();
  {
    const int b = t & 63, j = t >> 6;
    for (int c = j; c < OC; c += 8) {
      float p = E[c * 64 + b];
      #pragma unroll
      for (int w = 1; w < 8; ++w) p *= E[(w * OC + c) * 64 + b];
      R[c * 64 + b] = p;
    }
  }
  __syncthreads();
  if (t < 64) {
    const float Nv = R[NCLS * 64 + t];
    float K = Nv;
    #pragma unroll
    for (int c = 0; c < NCLS; ++c) K += R[c * 64 + t] - Nv;
    kv[t] = 1.0f / K;
  }
  __syncthreads();
  for (int idx = t; idx < 64 * OC; idx += 512) {
    const int b = idx / OC, c = idx - b * OC;
    const float Nv = R[NCLS * 64 + b];
    const float ik = kv[b];
    OUT[(size_t)bx * 64 * OC + idx] = (c < NCLS) ? (R[c * 64 + b] - Nv) * ik : Nv * ik;
  }
}

extern "C" void kernel_launch(void* const* d_in, const int* in_sizes, int n_in,
                              void* d_out, int out_size, void* d_ws, size_t ws_size,
                              hipStream_t stream) {
  (void)in_sizes; (void)n_in; (void)out_size; (void)ws_size;
  const float* X     = (const float*)d_in[0];
  const float* Wm    = (const float*)d_in[1];
  const float* BETA  = (const float*)d_in[2];
  const float* ALPHA = (const float*)d_in[3];
  const float* GAMMA = (const float*)d_in[4];
  float* OUT = (float*)d_out;

  char* ws = (char*)d_ws;
  unsigned short* PWH = (unsigned short*)(ws + OFF_PWH);
  unsigned short* PWL = (unsigned short*)(ws + OFF_PWL);
  float* VS = (float*)(ws + OFF_VS);
  float* WQ = (float*)(ws + OFF_WQ);
  float* AP = (float*)(ws + OFF_AP);
  float* G2 = (float*)(ws + OFF_G2);

  hipLaunchKernelGGL(prep, dim3(66), dim3(256), 0, stream,
                     Wm, BETA, ALPHA, GAMMA, PWH, PWL, WQ, VS, AP, G2);
  hipLaunchKernelGGL(evid64, dim3(NBATCH / 64), dim3(512), 0, stream,
                     X, PWH, PWL, VS, WQ, AP, G2, OUT);
}